// Round 1
// baseline (1088.141 us; speedup 1.0000x reference)
//
#include <hip/hip_runtime.h>

#define N_USERS 100000
#define N_ITEMS 50000
#define N_NODES 150000
#define NEDGES  4000000
#define EMB     64
#define BATCH   16384

// ---------------- CSR build ----------------

__global__ void k_zero(int* __restrict__ counts, int* __restrict__ cursor) {
    int i = blockIdx.x * blockDim.x + threadIdx.x;
    if (i < N_NODES) { counts[i] = 0; cursor[i] = 0; }
}

__global__ void k_hist(const int* __restrict__ erow, int* __restrict__ counts) {
    int e = blockIdx.x * blockDim.x + threadIdx.x;
    if (e < NEDGES) atomicAdd(&counts[erow[e]], 1);
}

// single-block exclusive scan of counts -> rowptr (N_NODES+1 entries)
__global__ __launch_bounds__(1024) void k_scan(const int* __restrict__ counts,
                                               int* __restrict__ rowptr) {
    __shared__ int lds[1024];
    const int t = threadIdx.x;
    const int CH = (N_NODES + 1023) / 1024;  // 147
    int beg = t * CH;
    int end = beg + CH; if (end > N_NODES) end = N_NODES;
    int s = 0;
    for (int i = beg; i < end; ++i) s += counts[i];
    lds[t] = s;
    __syncthreads();
    for (int off = 1; off < 1024; off <<= 1) {
        int u = (t >= off) ? lds[t - off] : 0;
        __syncthreads();
        lds[t] += u;
        __syncthreads();
    }
    int run = lds[t] - s;  // exclusive prefix of this chunk
    for (int i = beg; i < end; ++i) { rowptr[i] = run; run += counts[i]; }
    if (t == 1023) rowptr[N_NODES] = lds[1023];
}

__global__ void k_scatter(const int* __restrict__ erow, const int* __restrict__ ecol,
                          const float* __restrict__ eval, const int* __restrict__ rowptr,
                          int* __restrict__ cursor, int2* __restrict__ csr_ev) {
    int e = blockIdx.x * blockDim.x + threadIdx.x;
    if (e >= NEDGES) return;
    int r = erow[e];
    int pos = atomicAdd(&cursor[r], 1);
    int2 ev;
    ev.x = ecol[e];
    ev.y = __float_as_int(eval[e]);
    csr_ev[rowptr[r] + pos] = ev;
}

// ---------------- SpMM: one 16-lane group per row, float4 per lane ----------------

__global__ void k_spmm(const float* __restrict__ Ein, float* __restrict__ Eout,
                       const int* __restrict__ rowptr, const int2* __restrict__ csr_ev) {
    int g    = (blockIdx.x * blockDim.x + threadIdx.x) >> 4;  // row
    int lane = threadIdx.x & 15;
    if (g >= N_NODES) return;
    int beg = rowptr[g], end = rowptr[g + 1];
    float4 acc = make_float4(0.f, 0.f, 0.f, 0.f);
    for (int j = beg; j < end; ++j) {
        int2 ev = csr_ev[j];
        float v = __int_as_float(ev.y);
        float4 x = ((const float4*)(Ein + (size_t)ev.x * EMB))[lane];
        acc.x = fmaf(v, x.x, acc.x);
        acc.y = fmaf(v, x.y, acc.y);
        acc.z = fmaf(v, x.z, acc.z);
        acc.w = fmaf(v, x.w, acc.w);
    }
    ((float4*)(Eout + (size_t)g * EMB))[lane] = acc;
}

// ---------------- batch-row gather: init and accumulate ----------------

__global__ void k_gather_init(const float* __restrict__ E0, const int* __restrict__ ub,
                              const int* __restrict__ ib, float* __restrict__ U,
                              float* __restrict__ I) {
    int g    = (blockIdx.x * blockDim.x + threadIdx.x) >> 4;
    int lane = threadIdx.x & 15;
    if (g >= 2 * BATCH) return;
    if (g < BATCH) {
        int r = ub[g];
        ((float4*)(U + (size_t)g * EMB))[lane] =
            ((const float4*)(E0 + (size_t)r * EMB))[lane];
    } else {
        int b = g - BATCH;
        int r = N_USERS + ib[b];
        ((float4*)(I + (size_t)b * EMB))[lane] =
            ((const float4*)(E0 + (size_t)r * EMB))[lane];
    }
}

__global__ void k_gather_acc(const float* __restrict__ E, const int* __restrict__ ub,
                             const int* __restrict__ ib, float* __restrict__ U,
                             float* __restrict__ I) {
    int g    = (blockIdx.x * blockDim.x + threadIdx.x) >> 4;
    int lane = threadIdx.x & 15;
    if (g >= 2 * BATCH) return;
    if (g < BATCH) {
        int r = ub[g];
        float4 x = ((const float4*)(E + (size_t)r * EMB))[lane];
        float4* dst = (float4*)(U + (size_t)g * EMB) + lane;
        float4 a = *dst;
        a.x += x.x; a.y += x.y; a.z += x.z; a.w += x.w;
        *dst = a;
    } else {
        int b = g - BATCH;
        int r = N_USERS + ib[b];
        float4 x = ((const float4*)(E + (size_t)r * EMB))[lane];
        float4* dst = (float4*)(I + (size_t)b * EMB) + lane;
        float4 a = *dst;
        a.x += x.x; a.y += x.y; a.z += x.z; a.w += x.w;
        *dst = a;
    }
}

// ---------------- final dot ----------------

__global__ void k_dot(const float* __restrict__ U, const float* __restrict__ I,
                      float* __restrict__ out) {
    int g    = (blockIdx.x * blockDim.x + threadIdx.x) >> 4;
    int lane = threadIdx.x & 15;
    if (g >= BATCH) return;
    float4 a = ((const float4*)(U + (size_t)g * EMB))[lane];
    float4 b = ((const float4*)(I + (size_t)g * EMB))[lane];
    float p = a.x * b.x + a.y * b.y + a.z * b.z + a.w * b.w;
    for (int m = 1; m < 16; m <<= 1) p += __shfl_xor(p, m, 64);
    if (lane == 0) out[g] = p * (1.0f / 16.0f);  // 1/(K+1)^2
}

// ---------------- launch ----------------

static inline char* align16(char* p) {
    return (char*)(((uintptr_t)p + 15) & ~(uintptr_t)15);
}

extern "C" void kernel_launch(void* const* d_in, const int* in_sizes, int n_in,
                              void* d_out, int out_size, void* d_ws, size_t ws_size,
                              hipStream_t stream) {
    const float* E0   = (const float*)d_in[0];
    const float* eval = (const float*)d_in[1];
    const int*   erow = (const int*)d_in[2];
    const int*   ecol = (const int*)d_in[3];
    const int*   ub   = (const int*)d_in[4];
    const int*   ib   = (const int*)d_in[5];
    float* pred = (float*)d_out;

    char* p = (char*)d_ws;
    float* A      = (float*)p; p = align16(p + (size_t)N_NODES * EMB * 4);
    float* B      = (float*)p; p = align16(p + (size_t)N_NODES * EMB * 4);
    float* U      = (float*)p; p = align16(p + (size_t)BATCH * EMB * 4);
    float* I      = (float*)p; p = align16(p + (size_t)BATCH * EMB * 4);
    int*   counts = (int*)p;   p = align16(p + (size_t)N_NODES * 4);
    int*   cursor = (int*)p;   p = align16(p + (size_t)N_NODES * 4);
    int*   rowptr = (int*)p;   p = align16(p + (size_t)(N_NODES + 1) * 4);
    int2*  csr_ev = (int2*)p;  p = align16(p + (size_t)NEDGES * 8);

    const int BS = 256;
    // CSR build
    k_zero<<<(N_NODES + BS - 1) / BS, BS, 0, stream>>>(counts, cursor);
    k_hist<<<(NEDGES + BS - 1) / BS, BS, 0, stream>>>(erow, counts);
    k_scan<<<1, 1024, 0, stream>>>(counts, rowptr);
    k_scatter<<<(NEDGES + BS - 1) / BS, BS, 0, stream>>>(erow, ecol, eval, rowptr,
                                                         cursor, csr_ev);
    // batch accumulators start at E_0 rows
    k_gather_init<<<(2 * BATCH * 16 + BS - 1) / BS, BS, 0, stream>>>(E0, ub, ib, U, I);

    const int spmm_grid = (N_NODES * 16 + BS - 1) / BS;
    const int acc_grid  = (2 * BATCH * 16 + BS - 1) / BS;

    // hop 1: E0 -> A
    k_spmm<<<spmm_grid, BS, 0, stream>>>(E0, A, rowptr, csr_ev);
    k_gather_acc<<<acc_grid, BS, 0, stream>>>(A, ub, ib, U, I);
    // hop 2: A -> B
    k_spmm<<<spmm_grid, BS, 0, stream>>>(A, B, rowptr, csr_ev);
    k_gather_acc<<<acc_grid, BS, 0, stream>>>(B, ub, ib, U, I);
    // hop 3: B -> A
    k_spmm<<<spmm_grid, BS, 0, stream>>>(B, A, rowptr, csr_ev);
    k_gather_acc<<<acc_grid, BS, 0, stream>>>(A, ub, ib, U, I);

    // readout
    k_dot<<<(BATCH * 16 + BS - 1) / BS, BS, 0, stream>>>(U, I, pred);
}